// Round 9
// baseline (360.785 us; speedup 1.0000x reference)
//
#include <hip/hip_runtime.h>
#include <stdint.h>

#define M_SIMP 100000
#define MPAD   100064
#define NNZV   800000
#define KM5    5
#define CAP    40       // ELL row capacity; P(Binomial(800k,1e-5) deg >= 40) ~ 3e-16/row
#define NBH    3125     // build blocks per Laplacian
#define NBT    1563     // transpose / gemm blocks
#define NBW    40       // wb blocks
#define NBM    6250     // spmm blocks per Laplacian

typedef unsigned int u32;
typedef __attribute__((ext_vector_type(8))) short short8;
typedef __attribute__((ext_vector_type(4))) float f32x4;

__device__ __forceinline__ float bf2f(u32 u){ return __uint_as_float(u << 16); }
__device__ __forceinline__ u32 f2bf(float f){
    u32 u = __float_as_uint(f);
    return (u + 0x7FFFu + ((u >> 16) & 1u)) >> 16;   // RNE
}

// ======================= roles ==============================================

// single-pass ELL build: rank + scatter fused; no scans, no pe, no second pass
__device__ __forceinline__ void role_build(int h, int t, const int* __restrict__ idx,
                                           const float* __restrict__ val,
                                           int* __restrict__ cnt, uint2* __restrict__ cvE){
    int e = h * 256 + t;
    if (e < NNZV){
        int r = idx[e];
        int p = atomicAdd(&cnt[r], 1);          // device-scope, memory-side RMW
        uint2 o;
        o.x = (u32)idx[NNZV + e];               // column
        o.y = __float_as_uint(val[e]);          // value bits
        cvE[(size_t)r * CAP + p] = o;
    }
}

__device__ __forceinline__ void role_transpose(int g, int t, const float* __restrict__ x,
                                               u32* __restrict__ F0){
    __shared__ unsigned short s[64 * 130];
    int m0 = g * 64;
    int j  = t & 63;
    int r4 = t >> 6;
    #pragma unroll 4
    for (int it = 0; it < 32; ++it){
        int bc = it * 4 + r4;
        int m  = m0 + j;
        if (m < M_SIMP)
            s[j * 130 + bc] = (unsigned short)f2bf(x[(size_t)bc * M_SIMP + m]);
    }
    __syncthreads();
    #pragma unroll 4
    for (int it = 0; it < 16; ++it){
        int m  = it * 4 + r4;
        int gm = m0 + m;
        if (gm < M_SIMP){
            u32 lo = s[m * 130 + 2 * j];
            u32 hi = s[m * 130 + 2 * j + 1];
            F0[(size_t)gm * 64 + j] = lo | (hi << 16);
        }
    }
}

__device__ __forceinline__ void role_wb(int g, int t, const float* __restrict__ theta,
                                        u32* __restrict__ Wb){
    int idx = g * 256 + t;
    if (idx < KM5 * 64 * 32){
        int km = idx >> 11;
        int r  = idx & 2047;
        int o  = r >> 5;
        int i2 = (r & 31) * 2;
        int k  = (km == 0) ? 0 : ((km < 3) ? km : km + 1);   // 0,1,2,4,5
        float lo = theta[o * 384 + i2 * 6 + k];
        float hi = theta[o * 384 + (i2 + 1) * 6 + k];
        if (km == 0){
            lo += theta[o * 384 + i2 * 6 + 3];
            hi += theta[o * 384 + (i2 + 1) * 6 + 3];
        }
        Wb[idx] = f2bf(lo) | (f2bf(hi) << 16);
    }
}

#define ACC4(G0,G1,G2,G3,V0,V1,V2,V3)                                                              \
    a0 += V0*bf2f(G0.x&0xffffu) + V1*bf2f(G1.x&0xffffu) + V2*bf2f(G2.x&0xffffu) + V3*bf2f(G3.x&0xffffu); \
    a1 += V0*bf2f(G0.x>>16)     + V1*bf2f(G1.x>>16)     + V2*bf2f(G2.x>>16)     + V3*bf2f(G3.x>>16);     \
    a2 += V0*bf2f(G0.y&0xffffu) + V1*bf2f(G1.y&0xffffu) + V2*bf2f(G2.y&0xffffu) + V3*bf2f(G3.y&0xffffu); \
    a3 += V0*bf2f(G0.y>>16)     + V1*bf2f(G1.y>>16)     + V2*bf2f(G2.y>>16)     + V3*bf2f(G3.y>>16);     \
    a4 += V0*bf2f(G0.z&0xffffu) + V1*bf2f(G1.z&0xffffu) + V2*bf2f(G2.z&0xffffu) + V3*bf2f(G3.z&0xffffu); \
    a5 += V0*bf2f(G0.z>>16)     + V1*bf2f(G1.z>>16)     + V2*bf2f(G2.z>>16)     + V3*bf2f(G3.z>>16);     \
    a6 += V0*bf2f(G0.w&0xffffu) + V1*bf2f(G1.w&0xffffu) + V2*bf2f(G2.w&0xffffu) + V3*bf2f(G3.w&0xffffu); \
    a7 += V0*bf2f(G0.w>>16)     + V1*bf2f(G1.w>>16)     + V2*bf2f(G2.w>>16)     + V3*bf2f(G3.w>>16)

// SpMM from ELL: 16 rows/block, 16 lanes x uint4 per row.
// Software-pipelined: next 4-block's cv loads + gathers issued BEFORE consuming
// the current block -> 8 gathers in flight (counted-vmcnt pattern).
__device__ __forceinline__ void role_spmm(int blk, int t, const int* __restrict__ cnt,
                                          const uint2* __restrict__ cvE,
                                          const u32* __restrict__ fin,
                                          u32* __restrict__ fout){
    int sub = t >> 4;
    int l   = t & 15;
    int row = blk * 16 + sub;
    if (row >= M_SIMP) return;
    int deg = cnt[row];
    const uint2* __restrict__ cv = cvE + (size_t)row * CAP;
    float a0=0,a1=0,a2=0,a3=0,a4=0,a5=0,a6=0,a7=0;
    int j = 0;

    uint4 p01, p23;            // 4 cv entries: (c0,c1) in p01, (c2,c3) in p23
    uint4 g0, g1, g2, g3;      // gathers for current block
    if (deg >= 4){
        p01 = *(const uint4*)(cv + 0);
        p23 = *(const uint4*)(cv + 2);
        g0 = *(const uint4*)(fin + (size_t)p01.x * 64 + l * 4);
        g1 = *(const uint4*)(fin + (size_t)p01.z * 64 + l * 4);
        g2 = *(const uint4*)(fin + (size_t)p23.x * 64 + l * 4);
        g3 = *(const uint4*)(fin + (size_t)p23.z * 64 + l * 4);
    }
    for (; j + 8 <= deg; j += 4){
        // issue next block first (prefetch: stays outstanding across consume)
        uint4 q01 = *(const uint4*)(cv + j + 4);
        uint4 q23 = *(const uint4*)(cv + j + 6);
        uint4 h0 = *(const uint4*)(fin + (size_t)q01.x * 64 + l * 4);
        uint4 h1 = *(const uint4*)(fin + (size_t)q01.z * 64 + l * 4);
        uint4 h2 = *(const uint4*)(fin + (size_t)q23.x * 64 + l * 4);
        uint4 h3 = *(const uint4*)(fin + (size_t)q23.z * 64 + l * 4);
        // consume current block (waits only until g0..g3 landed)
        float v0 = __uint_as_float(p01.y), v1 = __uint_as_float(p01.w);
        float v2 = __uint_as_float(p23.y), v3 = __uint_as_float(p23.w);
        ACC4(g0, g1, g2, g3, v0, v1, v2, v3);
        p01 = q01; p23 = q23;
        g0 = h0; g1 = h1; g2 = h2; g3 = h3;
    }
    if (j + 4 <= deg){
        float v0 = __uint_as_float(p01.y), v1 = __uint_as_float(p01.w);
        float v2 = __uint_as_float(p23.y), v3 = __uint_as_float(p23.w);
        ACC4(g0, g1, g2, g3, v0, v1, v2, v3);
        j += 4;
    }
    for (; j < deg; j++){
        uint2 q = cv[j];
        float v = __uint_as_float(q.y);
        uint4 g = *(const uint4*)(fin + (size_t)q.x * 64 + l * 4);
        a0 += v*bf2f(g.x&0xffffu); a1 += v*bf2f(g.x>>16);
        a2 += v*bf2f(g.y&0xffffu); a3 += v*bf2f(g.y>>16);
        a4 += v*bf2f(g.z&0xffffu); a5 += v*bf2f(g.z>>16);
        a6 += v*bf2f(g.w&0xffffu); a7 += v*bf2f(g.w>>16);
    }
    uint4 o;
    o.x = f2bf(a0) | (f2bf(a1) << 16);
    o.y = f2bf(a2) | (f2bf(a3) << 16);
    o.z = f2bf(a4) | (f2bf(a5) << 16);
    o.w = f2bf(a6) | (f2bf(a7) << 16);
    *(uint4*)(fout + (size_t)row * 64 + l * 4) = o;
}

// ======================= kernels ============================================

// K1: build_Ll | build_Lu | transpose | wb (striped roles)
__global__ __launch_bounds__(256) void k_build(
    const int* __restrict__ Ll_idx, const float* __restrict__ Ll_val,
    int* __restrict__ cnt_l, uint2* __restrict__ cv_l,
    const int* __restrict__ Lu_idx, const float* __restrict__ Lu_val,
    int* __restrict__ cnt_u, uint2* __restrict__ cv_u,
    const float* __restrict__ x, u32* __restrict__ F0,
    const float* __restrict__ theta, u32* __restrict__ Wb)
{
    int bid = blockIdx.x, t = threadIdx.x;
    int r5 = bid % 5, g5 = bid / 5;          // grid 5*1603
    if (r5 < 2){
        int h = g5 * 2 + r5;
        if (h < NBH) role_build(h, t, Ll_idx, Ll_val, cnt_l, cv_l);
    } else if (r5 < 4){
        int h = g5 * 2 + (r5 - 2);
        if (h < NBH) role_build(h, t, Lu_idx, Lu_val, cnt_u, cv_u);
    } else if (g5 < NBT){
        role_transpose(g5, t, x, F0);
    } else {
        role_wb(g5 - NBT, t, theta, Wb);
    }
}

// K2/K3: both Laplacians' spmm in one dispatch
__global__ __launch_bounds__(256) void k_spmm2(
    const int* __restrict__ cnt_l, const uint2* __restrict__ cv_l,
    const u32* __restrict__ finL, u32* __restrict__ foutL,
    const int* __restrict__ cnt_u, const uint2* __restrict__ cv_u,
    const u32* __restrict__ finU, u32* __restrict__ foutU)
{
    if (blockIdx.y == 0) role_spmm(blockIdx.x, threadIdx.x, cnt_l, cv_l, finL, foutL);
    else                 role_spmm(blockIdx.x, threadIdx.x, cnt_u, cv_u, finU, foutU);
}

// K4: MFMA GEMM, LDS double-buffered via global_load_lds (round-4 proven)
__global__ __launch_bounds__(256, 4) void k_gemm(
    const u32* __restrict__ F0, const u32* __restrict__ F1, const u32* __restrict__ F2,
    const u32* __restrict__ F4, const u32* __restrict__ F5,
    const u32* __restrict__ Wb, const float* __restrict__ bias, float* __restrict__ out)
{
    __shared__ __align__(16) u32 sh[2][4096];   // 2 x 16 KB tiles
    int t    = threadIdx.x;
    int wave = t >> 6;
    int lane = t & 63;
    int q    = lane >> 4;
    int l16  = lane & 15;
    int bm   = blockIdx.x * 64;
    const u32* __restrict__ Fs[KM5] = {F0, F1, F2, F4, F5};

    int rowbase  = t >> 4;
    int srcc     = (t & 15) ^ ((t >> 4) & 15);  // swizzled source chunk-in-row
    int wavebase = (t & 192) * 4;

    f32x4 a00 = {0.f,0.f,0.f,0.f}, a10 = {0.f,0.f,0.f,0.f};
    f32x4 a20 = {0.f,0.f,0.f,0.f}, a30 = {0.f,0.f,0.f,0.f};
    f32x4 a01 = {0.f,0.f,0.f,0.f}, a11 = {0.f,0.f,0.f,0.f};
    f32x4 a21 = {0.f,0.f,0.f,0.f}, a31 = {0.f,0.f,0.f,0.f};

    int o_a = wave * 16 + l16;

    short8 wc0 = *(const short8*)(Wb + (0 * 64 + o_a) * 32 + 0 * 16 + q * 4);
    short8 wc1 = *(const short8*)(Wb + (0 * 64 + o_a) * 32 + 1 * 16 + q * 4);

    #pragma unroll
    for (int i = 0; i < 4; ++i){
        const u32* g = Fs[0] + (size_t)(bm + i * 16 + rowbase) * 64 + srcc * 4;
        __builtin_amdgcn_global_load_lds(g, &sh[0][i * 1024 + wavebase], 16, 0, 0);
    }
    asm volatile("s_waitcnt vmcnt(0)" ::: "memory");
    __syncthreads();

    #pragma unroll
    for (int km = 0; km < KM5; ++km){
        short8 wn0 = wc0, wn1 = wc1;
        if (km < KM5 - 1){
            wn0 = *(const short8*)(Wb + ((km + 1) * 64 + o_a) * 32 + 0 * 16 + q * 4);
            wn1 = *(const short8*)(Wb + ((km + 1) * 64 + o_a) * 32 + 1 * 16 + q * 4);
            const u32* __restrict__ Fn = Fs[km + 1];
            u32* dst = &sh[(km + 1) & 1][0];
            #pragma unroll
            for (int i = 0; i < 4; ++i){
                const u32* g = Fn + (size_t)(bm + i * 16 + rowbase) * 64 + srcc * 4;
                __builtin_amdgcn_global_load_lds(g, dst + i * 1024 + wavebase, 16, 0, 0);
            }
        }

        const u32* Lb = &sh[km & 1][0];
        #pragma unroll
        for (int h = 0; h < 2; ++h){
            short8 wa = h ? wc1 : wc0;
            int c0 = ((h * 4 + q) ^ l16) * 4;        // b=0 swizzled col
            int c1 = ((8 + h * 4 + q) ^ l16) * 4;    // b=1
            #pragma unroll
            for (int ms = 0; ms < 4; ++ms){
                const u32* rp_ = Lb + ms * 1024 + l16 * 64;
                short8 b0 = *(const short8*)(rp_ + c0);
                short8 b1 = *(const short8*)(rp_ + c1);
                if (ms == 0){ a00 = __builtin_amdgcn_mfma_f32_16x16x32_bf16(wa, b0, a00, 0, 0, 0);
                              a01 = __builtin_amdgcn_mfma_f32_16x16x32_bf16(wa, b1, a01, 0, 0, 0); }
                if (ms == 1){ a10 = __builtin_amdgcn_mfma_f32_16x16x32_bf16(wa, b0, a10, 0, 0, 0);
                              a11 = __builtin_amdgcn_mfma_f32_16x16x32_bf16(wa, b1, a11, 0, 0, 0); }
                if (ms == 2){ a20 = __builtin_amdgcn_mfma_f32_16x16x32_bf16(wa, b0, a20, 0, 0, 0);
                              a21 = __builtin_amdgcn_mfma_f32_16x16x32_bf16(wa, b1, a21, 0, 0, 0); }
                if (ms == 3){ a30 = __builtin_amdgcn_mfma_f32_16x16x32_bf16(wa, b0, a30, 0, 0, 0);
                              a31 = __builtin_amdgcn_mfma_f32_16x16x32_bf16(wa, b1, a31, 0, 0, 0); }
            }
        }

        asm volatile("s_waitcnt vmcnt(0)" ::: "memory");
        __syncthreads();
        wc0 = wn0; wc1 = wn1;
    }

    int ob = wave * 16 + q * 4;
    float bv0 = bias[ob], bv1 = bias[ob+1], bv2 = bias[ob+2], bv3 = bias[ob+3];
    f32x4 accs0[4] = {a00, a10, a20, a30};
    f32x4 accs1[4] = {a01, a11, a21, a31};
    #pragma unroll
    for (int ms = 0; ms < 4; ms++){
        int gm = bm + ms * 16 + l16;
        if (gm < M_SIMP){
            size_t base0 = (size_t)(0 * 64 + ob) * M_SIMP + gm;
            size_t base1 = (size_t)(1 * 64 + ob) * M_SIMP + gm;
            out[base0             ] = accs0[ms][0] + bv0;
            out[base0 + 1ul*M_SIMP] = accs0[ms][1] + bv1;
            out[base0 + 2ul*M_SIMP] = accs0[ms][2] + bv2;
            out[base0 + 3ul*M_SIMP] = accs0[ms][3] + bv3;
            out[base1             ] = accs1[ms][0] + bv0;
            out[base1 + 1ul*M_SIMP] = accs1[ms][1] + bv1;
            out[base1 + 2ul*M_SIMP] = accs1[ms][2] + bv2;
            out[base1 + 3ul*M_SIMP] = accs1[ms][3] + bv3;
        }
    }
}

extern "C" void kernel_launch(void* const* d_in, const int* in_sizes, int n_in,
                              void* d_out, int out_size, void* d_ws, size_t ws_size,
                              hipStream_t stream)
{
    const int*   Ll_idx = (const int*)d_in[0];
    const float* Ll_val = (const float*)d_in[1];
    const int*   Lu_idx = (const int*)d_in[2];
    const float* Lu_val = (const float*)d_in[3];
    const float* x      = (const float*)d_in[4];
    const float* theta  = (const float*)d_in[5];
    const float* bias   = (const float*)d_in[6];
    float* out = (float*)d_out;

    char* ws = (char*)d_ws;
    size_t off = 0;
    auto take = [&](size_t bytes) -> char* {
        char* p = ws + off;
        off = (off + bytes + 255) & ~(size_t)255;
        return p;
    };
    const size_t FB = (size_t)MPAD * 64 * 4;
    u32* F0 = (u32*)take(FB);
    u32* F1 = (u32*)take(FB);
    u32* F2 = (u32*)take(FB);
    u32* F4 = (u32*)take(FB);
    u32* F5 = (u32*)take(FB);
    u32* Wb = (u32*)take((size_t)KM5 * 64 * 32 * 4);
    int*   cnt_l = (int*)take((size_t)M_SIMP * 4);
    int*   cnt_u = (int*)take((size_t)M_SIMP * 4);
    uint2* cv_l  = (uint2*)take((size_t)M_SIMP * CAP * 8);
    uint2* cv_u  = (uint2*)take((size_t)M_SIMP * CAP * 8);

    hipMemsetAsync(cnt_l, 0, (size_t)M_SIMP * 4, stream);
    hipMemsetAsync(cnt_u, 0, (size_t)M_SIMP * 4, stream);

    // K1: build both Laplacians (single-pass ELL) | transpose | wb
    k_build<<<5 * (NBT + NBW), 256, 0, stream>>>(
        Ll_idx, Ll_val, cnt_l, cv_l,
        Lu_idx, Lu_val, cnt_u, cv_u,
        x, F0, theta, Wb);

    // K2: spmm1 both (F0 -> F1, F0 -> F4)
    dim3 gm(NBM, 2);
    k_spmm2<<<gm, 256, 0, stream>>>(cnt_l, cv_l, F0, F1,
                                    cnt_u, cv_u, F0, F4);
    // K3: spmm2 both (F1 -> F2, F4 -> F5)
    k_spmm2<<<gm, 256, 0, stream>>>(cnt_l, cv_l, F1, F2,
                                    cnt_u, cv_u, F4, F5);

    // K4: GEMM
    k_gemm<<<NBT, 256, 0, stream>>>(F0, F1, F2, F4, F5, Wb, bias, out);
}

// Round 10
// 353.387 us; speedup vs baseline: 1.0209x; 1.0209x over previous
//
#include <hip/hip_runtime.h>
#include <stdint.h>

#define M_SIMP 100000
#define MPAD   100064
#define NNZV   800000
#define KM5    5
#define CAP    40       // ELL row capacity; P(Binomial(800k,1e-5) deg >= 40) ~ 3e-16/row
#define NBH    3125     // build blocks per Laplacian
#define NBT    1563     // transpose / gemm blocks
#define NBW    40       // wb blocks
#define NBM    6250     // spmm blocks per Laplacian

typedef unsigned int u32;
typedef __attribute__((ext_vector_type(8))) short short8;
typedef __attribute__((ext_vector_type(4))) float f32x4;

__device__ __forceinline__ float bf2f(u32 u){ return __uint_as_float(u << 16); }
__device__ __forceinline__ u32 f2bf(float f){
    u32 u = __float_as_uint(f);
    return (u + 0x7FFFu + ((u >> 16) & 1u)) >> 16;   // RNE
}

// ======================= roles ==============================================

// single-pass ELL build: rank + scatter fused; no scans, no pe, no second pass
__device__ __forceinline__ void role_build(int h, int t, const int* __restrict__ idx,
                                           const float* __restrict__ val,
                                           int* __restrict__ cnt, uint2* __restrict__ cvE){
    int e = h * 256 + t;
    if (e < NNZV){
        int r = idx[e];
        int p = atomicAdd(&cnt[r], 1);          // device-scope, memory-side RMW
        uint2 o;
        o.x = (u32)idx[NNZV + e];               // column
        o.y = __float_as_uint(val[e]);          // value bits
        cvE[(size_t)r * CAP + p] = o;
    }
}

__device__ __forceinline__ void role_transpose(int g, int t, const float* __restrict__ x,
                                               u32* __restrict__ F0){
    __shared__ unsigned short s[64 * 130];
    int m0 = g * 64;
    int j  = t & 63;
    int r4 = t >> 6;
    #pragma unroll 4
    for (int it = 0; it < 32; ++it){
        int bc = it * 4 + r4;
        int m  = m0 + j;
        if (m < M_SIMP)
            s[j * 130 + bc] = (unsigned short)f2bf(x[(size_t)bc * M_SIMP + m]);
    }
    __syncthreads();
    #pragma unroll 4
    for (int it = 0; it < 16; ++it){
        int m  = it * 4 + r4;
        int gm = m0 + m;
        if (gm < M_SIMP){
            u32 lo = s[m * 130 + 2 * j];
            u32 hi = s[m * 130 + 2 * j + 1];
            F0[(size_t)gm * 64 + j] = lo | (hi << 16);
        }
    }
}

__device__ __forceinline__ void role_wb(int g, int t, const float* __restrict__ theta,
                                        u32* __restrict__ Wb){
    int idx = g * 256 + t;
    if (idx < KM5 * 64 * 32){
        int km = idx >> 11;
        int r  = idx & 2047;
        int o  = r >> 5;
        int i2 = (r & 31) * 2;
        int k  = (km == 0) ? 0 : ((km < 3) ? km : km + 1);   // 0,1,2,4,5
        float lo = theta[o * 384 + i2 * 6 + k];
        float hi = theta[o * 384 + (i2 + 1) * 6 + k];
        if (km == 0){
            lo += theta[o * 384 + i2 * 6 + 3];
            hi += theta[o * 384 + (i2 + 1) * 6 + 3];
        }
        Wb[idx] = f2bf(lo) | (f2bf(hi) << 16);
    }
}

// SpMM from ELL: 16 rows/block, 16 lanes x uint4 per row (round-8 verified form)
__device__ __forceinline__ void role_spmm(int blk, int t, const int* __restrict__ cnt,
                                          const uint2* __restrict__ cvE,
                                          const u32* __restrict__ fin,
                                          u32* __restrict__ fout){
    int sub = t >> 4;
    int l   = t & 15;
    int row = blk * 16 + sub;
    if (row >= M_SIMP) return;
    int deg = cnt[row];
    const uint2* __restrict__ cv = cvE + (size_t)row * CAP;
    float a0=0,a1=0,a2=0,a3=0,a4=0,a5=0,a6=0,a7=0;
    int j = 0;
    for (; j + 4 <= deg; j += 4){
        uint2 q0 = cv[j], q1 = cv[j+1], q2 = cv[j+2], q3 = cv[j+3];
        uint4 g0 = *(const uint4*)(fin + (size_t)q0.x * 64 + l * 4);
        uint4 g1 = *(const uint4*)(fin + (size_t)q1.x * 64 + l * 4);
        uint4 g2 = *(const uint4*)(fin + (size_t)q2.x * 64 + l * 4);
        uint4 g3 = *(const uint4*)(fin + (size_t)q3.x * 64 + l * 4);
        float v0 = __uint_as_float(q0.y), v1 = __uint_as_float(q1.y);
        float v2 = __uint_as_float(q2.y), v3 = __uint_as_float(q3.y);
        a0 += v0*bf2f(g0.x&0xffffu) + v1*bf2f(g1.x&0xffffu) + v2*bf2f(g2.x&0xffffu) + v3*bf2f(g3.x&0xffffu);
        a1 += v0*bf2f(g0.x>>16)     + v1*bf2f(g1.x>>16)     + v2*bf2f(g2.x>>16)     + v3*bf2f(g3.x>>16);
        a2 += v0*bf2f(g0.y&0xffffu) + v1*bf2f(g1.y&0xffffu) + v2*bf2f(g2.y&0xffffu) + v3*bf2f(g3.y&0xffffu);
        a3 += v0*bf2f(g0.y>>16)     + v1*bf2f(g1.y>>16)     + v2*bf2f(g2.y>>16)     + v3*bf2f(g3.y>>16);
        a4 += v0*bf2f(g0.z&0xffffu) + v1*bf2f(g1.z&0xffffu) + v2*bf2f(g2.z&0xffffu) + v3*bf2f(g3.z&0xffffu);
        a5 += v0*bf2f(g0.z>>16)     + v1*bf2f(g1.z>>16)     + v2*bf2f(g2.z>>16)     + v3*bf2f(g3.z>>16);
        a6 += v0*bf2f(g0.w&0xffffu) + v1*bf2f(g1.w&0xffffu) + v2*bf2f(g2.w&0xffffu) + v3*bf2f(g3.w&0xffffu);
        a7 += v0*bf2f(g0.w>>16)     + v1*bf2f(g1.w>>16)     + v2*bf2f(g2.w>>16)     + v3*bf2f(g3.w>>16);
    }
    for (; j < deg; j++){
        uint2 q = cv[j];
        float v = __uint_as_float(q.y);
        uint4 g = *(const uint4*)(fin + (size_t)q.x * 64 + l * 4);
        a0 += v*bf2f(g.x&0xffffu); a1 += v*bf2f(g.x>>16);
        a2 += v*bf2f(g.y&0xffffu); a3 += v*bf2f(g.y>>16);
        a4 += v*bf2f(g.z&0xffffu); a5 += v*bf2f(g.z>>16);
        a6 += v*bf2f(g.w&0xffffu); a7 += v*bf2f(g.w>>16);
    }
    uint4 o;
    o.x = f2bf(a0) | (f2bf(a1) << 16);
    o.y = f2bf(a2) | (f2bf(a3) << 16);
    o.z = f2bf(a4) | (f2bf(a5) << 16);
    o.w = f2bf(a6) | (f2bf(a7) << 16);
    *(uint4*)(fout + (size_t)row * 64 + l * 4) = o;
}

// ======================= kernels ============================================

// K1: build_Ll | build_Lu | transpose | wb (striped roles)
__global__ __launch_bounds__(256) void k_build(
    const int* __restrict__ Ll_idx, const float* __restrict__ Ll_val,
    int* __restrict__ cnt_l, uint2* __restrict__ cv_l,
    const int* __restrict__ Lu_idx, const float* __restrict__ Lu_val,
    int* __restrict__ cnt_u, uint2* __restrict__ cv_u,
    const float* __restrict__ x, u32* __restrict__ F0,
    const float* __restrict__ theta, u32* __restrict__ Wb)
{
    int bid = blockIdx.x, t = threadIdx.x;
    int r5 = bid % 5, g5 = bid / 5;          // grid 5*1603
    if (r5 < 2){
        int h = g5 * 2 + r5;
        if (h < NBH) role_build(h, t, Ll_idx, Ll_val, cnt_l, cv_l);
    } else if (r5 < 4){
        int h = g5 * 2 + (r5 - 2);
        if (h < NBH) role_build(h, t, Lu_idx, Lu_val, cnt_u, cv_u);
    } else if (g5 < NBT){
        role_transpose(g5, t, x, F0);
    } else {
        role_wb(g5 - NBT, t, theta, Wb);
    }
}

// K2/K3: both Laplacians' spmm in one dispatch
__global__ __launch_bounds__(256) void k_spmm2(
    const int* __restrict__ cnt_l, const uint2* __restrict__ cv_l,
    const u32* __restrict__ finL, u32* __restrict__ foutL,
    const int* __restrict__ cnt_u, const uint2* __restrict__ cv_u,
    const u32* __restrict__ finU, u32* __restrict__ foutU)
{
    if (blockIdx.y == 0) role_spmm(blockIdx.x, threadIdx.x, cnt_l, cv_l, finL, foutL);
    else                 role_spmm(blockIdx.x, threadIdx.x, cnt_u, cv_u, finU, foutU);
}

// K4: MFMA GEMM, LDS double-buffered via global_load_lds (round-4 proven)
__global__ __launch_bounds__(256, 4) void k_gemm(
    const u32* __restrict__ F0, const u32* __restrict__ F1, const u32* __restrict__ F2,
    const u32* __restrict__ F4, const u32* __restrict__ F5,
    const u32* __restrict__ Wb, const float* __restrict__ bias, float* __restrict__ out)
{
    __shared__ __align__(16) u32 sh[2][4096];   // 2 x 16 KB tiles
    int t    = threadIdx.x;
    int wave = t >> 6;
    int lane = t & 63;
    int q    = lane >> 4;
    int l16  = lane & 15;
    int bm   = blockIdx.x * 64;
    const u32* __restrict__ Fs[KM5] = {F0, F1, F2, F4, F5};

    int rowbase  = t >> 4;
    int srcc     = (t & 15) ^ ((t >> 4) & 15);  // swizzled source chunk-in-row
    int wavebase = (t & 192) * 4;

    f32x4 a00 = {0.f,0.f,0.f,0.f}, a10 = {0.f,0.f,0.f,0.f};
    f32x4 a20 = {0.f,0.f,0.f,0.f}, a30 = {0.f,0.f,0.f,0.f};
    f32x4 a01 = {0.f,0.f,0.f,0.f}, a11 = {0.f,0.f,0.f,0.f};
    f32x4 a21 = {0.f,0.f,0.f,0.f}, a31 = {0.f,0.f,0.f,0.f};

    int o_a = wave * 16 + l16;

    short8 wc0 = *(const short8*)(Wb + (0 * 64 + o_a) * 32 + 0 * 16 + q * 4);
    short8 wc1 = *(const short8*)(Wb + (0 * 64 + o_a) * 32 + 1 * 16 + q * 4);

    #pragma unroll
    for (int i = 0; i < 4; ++i){
        const u32* g = Fs[0] + (size_t)(bm + i * 16 + rowbase) * 64 + srcc * 4;
        __builtin_amdgcn_global_load_lds(g, &sh[0][i * 1024 + wavebase], 16, 0, 0);
    }
    asm volatile("s_waitcnt vmcnt(0)" ::: "memory");
    __syncthreads();

    #pragma unroll
    for (int km = 0; km < KM5; ++km){
        short8 wn0 = wc0, wn1 = wc1;
        if (km < KM5 - 1){
            wn0 = *(const short8*)(Wb + ((km + 1) * 64 + o_a) * 32 + 0 * 16 + q * 4);
            wn1 = *(const short8*)(Wb + ((km + 1) * 64 + o_a) * 32 + 1 * 16 + q * 4);
            const u32* __restrict__ Fn = Fs[km + 1];
            u32* dst = &sh[(km + 1) & 1][0];
            #pragma unroll
            for (int i = 0; i < 4; ++i){
                const u32* g = Fn + (size_t)(bm + i * 16 + rowbase) * 64 + srcc * 4;
                __builtin_amdgcn_global_load_lds(g, dst + i * 1024 + wavebase, 16, 0, 0);
            }
        }

        const u32* Lb = &sh[km & 1][0];
        #pragma unroll
        for (int h = 0; h < 2; ++h){
            short8 wa = h ? wc1 : wc0;
            int c0 = ((h * 4 + q) ^ l16) * 4;        // b=0 swizzled col
            int c1 = ((8 + h * 4 + q) ^ l16) * 4;    // b=1
            #pragma unroll
            for (int ms = 0; ms < 4; ++ms){
                const u32* rp_ = Lb + ms * 1024 + l16 * 64;
                short8 b0 = *(const short8*)(rp_ + c0);
                short8 b1 = *(const short8*)(rp_ + c1);
                if (ms == 0){ a00 = __builtin_amdgcn_mfma_f32_16x16x32_bf16(wa, b0, a00, 0, 0, 0);
                              a01 = __builtin_amdgcn_mfma_f32_16x16x32_bf16(wa, b1, a01, 0, 0, 0); }
                if (ms == 1){ a10 = __builtin_amdgcn_mfma_f32_16x16x32_bf16(wa, b0, a10, 0, 0, 0);
                              a11 = __builtin_amdgcn_mfma_f32_16x16x32_bf16(wa, b1, a11, 0, 0, 0); }
                if (ms == 2){ a20 = __builtin_amdgcn_mfma_f32_16x16x32_bf16(wa, b0, a20, 0, 0, 0);
                              a21 = __builtin_amdgcn_mfma_f32_16x16x32_bf16(wa, b1, a21, 0, 0, 0); }
                if (ms == 3){ a30 = __builtin_amdgcn_mfma_f32_16x16x32_bf16(wa, b0, a30, 0, 0, 0);
                              a31 = __builtin_amdgcn_mfma_f32_16x16x32_bf16(wa, b1, a31, 0, 0, 0); }
            }
        }

        asm volatile("s_waitcnt vmcnt(0)" ::: "memory");
        __syncthreads();
        wc0 = wn0; wc1 = wn1;
    }

    int ob = wave * 16 + q * 4;
    float bv0 = bias[ob], bv1 = bias[ob+1], bv2 = bias[ob+2], bv3 = bias[ob+3];
    f32x4 accs0[4] = {a00, a10, a20, a30};
    f32x4 accs1[4] = {a01, a11, a21, a31};
    #pragma unroll
    for (int ms = 0; ms < 4; ms++){
        int gm = bm + ms * 16 + l16;
        if (gm < M_SIMP){
            size_t base0 = (size_t)(0 * 64 + ob) * M_SIMP + gm;
            size_t base1 = (size_t)(1 * 64 + ob) * M_SIMP + gm;
            out[base0             ] = accs0[ms][0] + bv0;
            out[base0 + 1ul*M_SIMP] = accs0[ms][1] + bv1;
            out[base0 + 2ul*M_SIMP] = accs0[ms][2] + bv2;
            out[base0 + 3ul*M_SIMP] = accs0[ms][3] + bv3;
            out[base1             ] = accs1[ms][0] + bv0;
            out[base1 + 1ul*M_SIMP] = accs1[ms][1] + bv1;
            out[base1 + 2ul*M_SIMP] = accs1[ms][2] + bv2;
            out[base1 + 3ul*M_SIMP] = accs1[ms][3] + bv3;
        }
    }
}

extern "C" void kernel_launch(void* const* d_in, const int* in_sizes, int n_in,
                              void* d_out, int out_size, void* d_ws, size_t ws_size,
                              hipStream_t stream)
{
    const int*   Ll_idx = (const int*)d_in[0];
    const float* Ll_val = (const float*)d_in[1];
    const int*   Lu_idx = (const int*)d_in[2];
    const float* Lu_val = (const float*)d_in[3];
    const float* x      = (const float*)d_in[4];
    const float* theta  = (const float*)d_in[5];
    const float* bias   = (const float*)d_in[6];
    float* out = (float*)d_out;

    char* ws = (char*)d_ws;
    size_t off = 0;
    auto take = [&](size_t bytes) -> char* {
        char* p = ws + off;
        off = (off + bytes + 255) & ~(size_t)255;
        return p;
    };
    const size_t FB = (size_t)MPAD * 64 * 4;
    u32* F0 = (u32*)take(FB);
    u32* F1 = (u32*)take(FB);
    u32* F2 = (u32*)take(FB);
    u32* F4 = (u32*)take(FB);
    u32* F5 = (u32*)take(FB);
    u32* Wb = (u32*)take((size_t)KM5 * 64 * 32 * 4);
    int*   cnt_l = (int*)take((size_t)M_SIMP * 4);
    int*   cnt_u = (int*)take((size_t)M_SIMP * 4);
    uint2* cv_l  = (uint2*)take((size_t)M_SIMP * CAP * 8);
    uint2* cv_u  = (uint2*)take((size_t)M_SIMP * CAP * 8);

    hipMemsetAsync(cnt_l, 0, (size_t)M_SIMP * 4, stream);
    hipMemsetAsync(cnt_u, 0, (size_t)M_SIMP * 4, stream);

    // K1: build both Laplacians (single-pass ELL) | transpose | wb
    k_build<<<5 * (NBT + NBW), 256, 0, stream>>>(
        Ll_idx, Ll_val, cnt_l, cv_l,
        Lu_idx, Lu_val, cnt_u, cv_u,
        x, F0, theta, Wb);

    // K2: spmm1 both (F0 -> F1, F0 -> F4)
    dim3 gm(NBM, 2);
    k_spmm2<<<gm, 256, 0, stream>>>(cnt_l, cv_l, F0, F1,
                                    cnt_u, cv_u, F0, F4);
    // K3: spmm2 both (F1 -> F2, F4 -> F5)
    k_spmm2<<<gm, 256, 0, stream>>>(cnt_l, cv_l, F1, F2,
                                    cnt_u, cv_u, F4, F5);

    // K4: GEMM
    k_gemm<<<NBT, 256, 0, stream>>>(F0, F1, F2, F4, F5, Wb, bias, out);
}